// Round 1
// baseline (277.330 us; speedup 1.0000x reference)
//
#include <hip/hip_runtime.h>
#include <cstdint>

// CrossLayerAttention on MI355X (gfx950).
// B=4 S=1024 H=2048 NH=16 HD=128.
// Pipeline: cvt(hs,wq,wo)->bf16; gemm_bt (q=hs@wq.T+bq, bf16 out);
// rope+relayout -> q_bf[b,h,s,d]; flash attention (causal, online softmax);
// gemm_bt (out = attn@wo.T + bo, fp32 out).

typedef unsigned short u16;
typedef __bf16 bf16x8 __attribute__((ext_vector_type(8)));
typedef float  f32x4  __attribute__((ext_vector_type(4)));

__device__ __forceinline__ u16 f2bf(float f) {
  uint32_t u = __builtin_bit_cast(uint32_t, f);
  u += 0x7fffu + ((u >> 16) & 1u);   // RNE; inputs are finite
  return (u16)(u >> 16);
}
__device__ __forceinline__ float bf2f(u16 h) {
  uint32_t u = ((uint32_t)h) << 16;
  return __builtin_bit_cast(float, u);
}

// ---------------- fp32 -> bf16 convert, 4 elems/thread ----------------
__global__ __launch_bounds__(256) void cvt_kernel(const float* __restrict__ in,
                                                  u16* __restrict__ out, int n4) {
  int i = blockIdx.x * 256 + threadIdx.x;
  if (i < n4) {
    float4 v = ((const float4*)in)[i];
    ushort4 o;
    o.x = f2bf(v.x); o.y = f2bf(v.y); o.z = f2bf(v.z); o.w = f2bf(v.w);
    ((ushort4*)out)[i] = o;
  }
}

// ---------------- GEMM: C[M,N] = A[M,K] @ B[N,K]^T + bias ----------------
// 128x128 tile, BK=32, 256 threads = 4 waves (2x2), wave tile 64x64 (4x4 MFMA frags).
// Verified m89 layouts: a[i]=A[l&15][(l>>4)*8+i]; b[i]=B[k][l&15]; d[i]=D[(l>>4)*4+i][l&15].
template<bool OUT_BF16>
__global__ __launch_bounds__(256)
void gemm_bt(const u16* __restrict__ A, const u16* __restrict__ Bm,
             const float* __restrict__ bias, void* __restrict__ Cout,
             int M, int N, int K) {
  __shared__ __align__(16) u16 As[128 * 32];
  __shared__ __align__(16) u16 Bs[128 * 32];
  const int t = threadIdx.x;
  const int lane = t & 63;
  const int w = t >> 6;
  const int row0 = blockIdx.x * 128, col0 = blockIdx.y * 128;
  const int wr = (w >> 1) * 64, wc = (w & 1) * 64;
  const int fr = lane & 15, fg = lane >> 4;
  const int fk = fg * 8;
  const int sr = t >> 2, sk = (t & 3) * 8;   // staging: row, k-offset
  f32x4 acc[4][4] = {};

  for (int k0 = 0; k0 < K; k0 += 32) {
    __syncthreads();
    ((int4*)As)[t]       = *(const int4*)(A  + (size_t)(row0 + sr) * K       + k0 + sk);
    ((int4*)As)[256 + t] = *(const int4*)(A  + (size_t)(row0 + 64 + sr) * K  + k0 + sk);
    ((int4*)Bs)[t]       = *(const int4*)(Bm + (size_t)(col0 + sr) * K       + k0 + sk);
    ((int4*)Bs)[256 + t] = *(const int4*)(Bm + (size_t)(col0 + 64 + sr) * K  + k0 + sk);
    __syncthreads();
    bf16x8 af[4], bq[4];
#pragma unroll
    for (int i = 0; i < 4; i++) af[i] = *(const bf16x8*)&As[(wr + i * 16 + fr) * 32 + fk];
#pragma unroll
    for (int i = 0; i < 4; i++) bq[i] = *(const bf16x8*)&Bs[(wc + i * 16 + fr) * 32 + fk];
#pragma unroll
    for (int mi = 0; mi < 4; mi++)
#pragma unroll
      for (int ni = 0; ni < 4; ni++)
        acc[mi][ni] = __builtin_amdgcn_mfma_f32_16x16x32_bf16(af[mi], bq[ni], acc[mi][ni], 0, 0, 0);
  }

#pragma unroll
  for (int mi = 0; mi < 4; mi++)
#pragma unroll
    for (int ni = 0; ni < 4; ni++) {
      int col = col0 + wc + ni * 16 + fr;
      float bv = bias[col];
#pragma unroll
      for (int i = 0; i < 4; i++) {
        int row = row0 + wr + mi * 16 + fg * 4 + i;
        float v = acc[mi][ni][i] + bv;
        if constexpr (OUT_BF16) ((u16*)Cout)[(size_t)row * N + col] = f2bf(v);
        else                    ((float*)Cout)[(size_t)row * N + col] = v;
      }
    }
}

// ---------------- RoPE + relayout: q_proj[b*S+s][h*128+d] -> q_bf[bh][s][d] ----------------
__global__ __launch_bounds__(256) void rope_kernel(const u16* __restrict__ qp,
                                                   const float* __restrict__ cosb,
                                                   const float* __restrict__ sinb,
                                                   u16* __restrict__ qout) {
  int tid = blockIdx.x * 256 + threadIdx.x;     // B*S*NH*16 threads
  int p4 = tid & 15;
  int h  = (tid >> 4) & 15;
  int s  = (tid >> 8) & 1023;
  int b  = tid >> 18;
  int d0 = p4 * 4;                              // 0..60 (first half pairs)
  size_t qoff = ((size_t)(b * 1024 + s)) * 2048 + h * 128 + d0;
  ushort4 q1 = *(const ushort4*)(qp + qoff);        // q[d0..d0+3]
  ushort4 q2 = *(const ushort4*)(qp + qoff + 64);   // q[d0+64..]
  float4 c  = *(const float4*)(cosb + s * 128 + d0);  // cos[s][d]==cos[s][d+64]
  float4 sn = *(const float4*)(sinb + s * 128 + d0);
  float q1f[4] = {bf2f(q1.x), bf2f(q1.y), bf2f(q1.z), bf2f(q1.w)};
  float q2f[4] = {bf2f(q2.x), bf2f(q2.y), bf2f(q2.z), bf2f(q2.w)};
  float cc[4]  = {c.x, c.y, c.z, c.w};
  float ssv[4] = {sn.x, sn.y, sn.z, sn.w};
  ushort4 o1, o2;
  o1.x = f2bf(q1f[0] * cc[0] - q2f[0] * ssv[0]);
  o1.y = f2bf(q1f[1] * cc[1] - q2f[1] * ssv[1]);
  o1.z = f2bf(q1f[2] * cc[2] - q2f[2] * ssv[2]);
  o1.w = f2bf(q1f[3] * cc[3] - q2f[3] * ssv[3]);
  o2.x = f2bf(q2f[0] * cc[0] + q1f[0] * ssv[0]);
  o2.y = f2bf(q2f[1] * cc[1] + q1f[1] * ssv[1]);
  o2.z = f2bf(q2f[2] * cc[2] + q1f[2] * ssv[2]);
  o2.w = f2bf(q2f[3] * cc[3] + q1f[3] * ssv[3]);
  size_t ooff = ((size_t)(b * 16 + h) * 1024 + s) * 128 + d0;
  *(ushort4*)(qout + ooff)      = o1;
  *(ushort4*)(qout + ooff + 64) = o2;
}

// ---------------- Flash attention, causal ----------------
// grid (bh=64, qt=8); 256 thr = 4 waves, wave owns 32 q-rows; BQ=128, BKV=64.
// K^T and V^T staged in LDS with padded strides (rows 16B-aligned, bank-spread).
__global__ __launch_bounds__(256)
void attn_kernel(const u16* __restrict__ qbf, const float* __restrict__ key,
                 const float* __restrict__ val, u16* __restrict__ aout) {
  __shared__ __align__(16) u16 kT[64 * 136];      // [j][d] stride 136 (272B = 17*16)
  __shared__ __align__(16) u16 vT[128 * 72];      // [d][s] stride 72  (144B = 9*16)
  __shared__ __align__(16) u16 Pl[4 * 32 * 72];   // per-wave [32][72]
  const int t = threadIdx.x, lane = t & 63, w = t >> 6;
  const int bh = blockIdx.x, qt = blockIdx.y;
  const int q0 = qt * 128;
  const int fr = lane & 15, fg = lane >> 4;
  const float scale = 0.088388347648318447f;      // 1/sqrt(128)

  // Q fragments in registers: rows w*32 + mi*16 + fr, k = kb*32 + fg*8
  bf16x8 qf[2][4];
#pragma unroll
  for (int mi = 0; mi < 2; mi++)
#pragma unroll
    for (int kb = 0; kb < 4; kb++)
      qf[mi][kb] = *(const bf16x8*)&qbf[((size_t)bh * 1024 + q0 + w * 32 + mi * 16 + fr) * 128 + kb * 32 + fg * 8];

  f32x4 acc_o[2][8] = {};
  float mrow[2][4], lrow[2][4];
#pragma unroll
  for (int mi = 0; mi < 2; mi++)
#pragma unroll
    for (int i = 0; i < 4; i++) { mrow[mi][i] = -1e30f; lrow[mi][i] = 0.f; }

  const int ntiles = 2 * qt + 2;
  for (int kt = 0; kt < ntiles; kt++) {
    __syncthreads();
    // stage K^T: key[bh][d][kt*64+j] -> kT[j][d]
    {
      int jj = (t & 15) * 4, dd = t >> 4;
#pragma unroll
      for (int p = 0; p < 8; p++, dd += 16) {
        float4 kv = *(const float4*)(key + ((size_t)bh * 128 + dd) * 1024 + kt * 64 + jj);
        kT[(jj + 0) * 136 + dd] = f2bf(kv.x);
        kT[(jj + 1) * 136 + dd] = f2bf(kv.y);
        kT[(jj + 2) * 136 + dd] = f2bf(kv.z);
        kT[(jj + 3) * 136 + dd] = f2bf(kv.w);
      }
      // stage V^T: val[bh][kt*64+s][d] -> vT[d][s]
      int d4 = (t & 31) * 4, ss = t >> 5;
#pragma unroll
      for (int p = 0; p < 8; p++, ss += 8) {
        float4 vv = *(const float4*)(val + ((size_t)bh * 1024 + kt * 64 + ss) * 128 + d4);
        vT[(d4 + 0) * 72 + ss] = f2bf(vv.x);
        vT[(d4 + 1) * 72 + ss] = f2bf(vv.y);
        vT[(d4 + 2) * 72 + ss] = f2bf(vv.z);
        vT[(d4 + 3) * 72 + ss] = f2bf(vv.w);
      }
    }
    __syncthreads();

    // scores: S = Q @ K   (wave rows: 2 frags x 4 col-frags, K-dim 128 in 4 steps)
    f32x4 sa[2][4] = {};
#pragma unroll
    for (int kb = 0; kb < 4; kb++) {
      bf16x8 kf[4];
#pragma unroll
      for (int ni = 0; ni < 4; ni++)
        kf[ni] = *(const bf16x8*)&kT[(ni * 16 + fr) * 136 + kb * 32 + fg * 8];
#pragma unroll
      for (int mi = 0; mi < 2; mi++)
#pragma unroll
        for (int ni = 0; ni < 4; ni++)
          sa[mi][ni] = __builtin_amdgcn_mfma_f32_16x16x32_bf16(qf[mi][kb], kf[ni], sa[mi][ni], 0, 0, 0);
    }

    // online softmax per row; rows = q0 + w*32 + mi*16 + fg*4 + i
#pragma unroll
    for (int mi = 0; mi < 2; mi++) {
      float tmax[4] = {-1e30f, -1e30f, -1e30f, -1e30f};
#pragma unroll
      for (int i = 0; i < 4; i++) {
        int rowg = q0 + w * 32 + mi * 16 + fg * 4 + i;
#pragma unroll
        for (int ni = 0; ni < 4; ni++) {
          int colg = kt * 64 + ni * 16 + fr;
          float s = sa[mi][ni][i] * scale + (colg > rowg ? -1e9f : 0.f);
          sa[mi][ni][i] = s;
          tmax[i] = fmaxf(tmax[i], s);
        }
      }
#pragma unroll
      for (int msk = 1; msk < 16; msk <<= 1)
#pragma unroll
        for (int i = 0; i < 4; i++) tmax[i] = fmaxf(tmax[i], __shfl_xor(tmax[i], msk));
      float corr[4], rsum[4] = {0.f, 0.f, 0.f, 0.f};
#pragma unroll
      for (int i = 0; i < 4; i++) {
        float mnew = fmaxf(mrow[mi][i], tmax[i]);
        corr[i] = __expf(mrow[mi][i] - mnew);
        mrow[mi][i] = mnew;
      }
#pragma unroll
      for (int ni = 0; ni < 4; ni++)
#pragma unroll
        for (int i = 0; i < 4; i++) {
          float p = __expf(sa[mi][ni][i] - mrow[mi][i]);
          sa[mi][ni][i] = p;
          rsum[i] += p;
        }
#pragma unroll
      for (int msk = 1; msk < 16; msk <<= 1)
#pragma unroll
        for (int i = 0; i < 4; i++) rsum[i] += __shfl_xor(rsum[i], msk);
#pragma unroll
      for (int i = 0; i < 4; i++) lrow[mi][i] = lrow[mi][i] * corr[i] + rsum[i];
#pragma unroll
      for (int ni = 0; ni < 8; ni++)
#pragma unroll
        for (int i = 0; i < 4; i++) acc_o[mi][ni][i] *= corr[i];
      // write P (bf16) to this wave's LDS region
#pragma unroll
      for (int ni = 0; ni < 4; ni++)
#pragma unroll
        for (int i = 0; i < 4; i++)
          Pl[w * 32 * 72 + (mi * 16 + fg * 4 + i) * 72 + ni * 16 + fr] = f2bf(sa[mi][ni][i]);
    }
    __syncthreads();

    // PV: O += P @ V  (K-dim 64 in 2 steps, 8 d-frags)
#pragma unroll
    for (int kb2 = 0; kb2 < 2; kb2++) {
      bf16x8 pf[2];
#pragma unroll
      for (int mi = 0; mi < 2; mi++)
        pf[mi] = *(const bf16x8*)&Pl[w * 32 * 72 + (mi * 16 + fr) * 72 + kb2 * 32 + fg * 8];
#pragma unroll
      for (int ni = 0; ni < 8; ni++) {
        bf16x8 vf = *(const bf16x8*)&vT[(ni * 16 + fr) * 72 + kb2 * 32 + fg * 8];
#pragma unroll
        for (int mi = 0; mi < 2; mi++)
          acc_o[mi][ni] = __builtin_amdgcn_mfma_f32_16x16x32_bf16(pf[mi], vf, acc_o[mi][ni], 0, 0, 0);
      }
    }
  }

  // epilogue: normalize, write attn_bf[((b*S+s)*NH+h)*HD + d]
  const int b = bh >> 4, h = bh & 15;
#pragma unroll
  for (int mi = 0; mi < 2; mi++)
#pragma unroll
    for (int i = 0; i < 4; i++) {
      int s = q0 + w * 32 + mi * 16 + fg * 4 + i;
      float inv = 1.f / lrow[mi][i];
#pragma unroll
      for (int ni = 0; ni < 8; ni++) {
        int d = ni * 16 + fr;
        aout[(((size_t)b * 1024 + s) * 16 + h) * 128 + d] = f2bf(acc_o[mi][ni][i] * inv);
      }
    }
}

// ---------------- launcher ----------------
extern "C" void kernel_launch(void* const* d_in, const int* in_sizes, int n_in,
                              void* d_out, int out_size, void* d_ws, size_t ws_size,
                              hipStream_t stream) {
  const float* hs  = (const float*)d_in[0];
  const float* key = (const float*)d_in[1];
  const float* val = (const float*)d_in[2];
  // d_in[3]: attention_mask — reproduced analytically (causal, -1e9)
  const float* rc  = (const float*)d_in[4];
  const float* rs  = (const float*)d_in[5];
  const float* wq  = (const float*)d_in[6];
  const float* bq  = (const float*)d_in[7];
  const float* wo  = (const float*)d_in[8];
  const float* bo  = (const float*)d_in[9];
  float* out = (float*)d_out;

  char* ws = (char*)d_ws;
  u16* hs_bf   = (u16*)(ws);                 // 16,777,216 B
  u16* wq_bf   = (u16*)(ws + 16777216);      //  8,388,608 B
  u16* wo_bf   = (u16*)(ws + 25165824);      //  8,388,608 B
  u16* q_proj  = (u16*)(ws + 33554432);      // 16,777,216 B
  u16* q_bf    = (u16*)(ws + 50331648);      // 16,777,216 B
  u16* attn_bf = (u16*)(ws + 67108864);      // 16,777,216 B  (total 80 MiB)

  cvt_kernel<<<8192, 256, 0, stream>>>(hs, hs_bf, 8388608 / 4);
  cvt_kernel<<<4096, 256, 0, stream>>>(wq, wq_bf, 4194304 / 4);
  cvt_kernel<<<4096, 256, 0, stream>>>(wo, wo_bf, 4194304 / 4);

  gemm_bt<true><<<dim3(32, 16), 256, 0, stream>>>(hs_bf, wq_bf, bq, q_proj, 4096, 2048, 2048);
  rope_kernel<<<4096, 256, 0, stream>>>(q_proj, rc, rs, q_bf);
  attn_kernel<<<dim3(64, 8), 256, 0, stream>>>(q_bf, key, val, attn_bf);
  gemm_bt<false><<<dim3(32, 16), 256, 0, stream>>>(attn_bf, wo_bf, bo, out, 4096, 2048, 2048);
}

// Round 2
// 210.648 us; speedup vs baseline: 1.3166x; 1.3166x over previous
//
#include <hip/hip_runtime.h>
#include <cstdint>

// CrossLayerAttention on MI355X (gfx950).  B=4 S=1024 H=2048 NH=16 HD=128.
// R2: pre-transposed bf16 K/V, vectorized attn staging, balanced causal grid,
//     global_load_lds GEMMs (m97 structure).

typedef unsigned short u16;
typedef __bf16 bf16x8 __attribute__((ext_vector_type(8)));
typedef float  f32x4  __attribute__((ext_vector_type(4)));

__device__ __forceinline__ u16 f2bf(float f) {
  uint32_t u = __builtin_bit_cast(uint32_t, f);
  u += 0x7fffu + ((u >> 16) & 1u);   // RNE; inputs finite
  return (u16)(u >> 16);
}
__device__ __forceinline__ float bf2f(u16 h) {
  uint32_t u = ((uint32_t)h) << 16;
  return __builtin_bit_cast(float, u);
}
__device__ __forceinline__ void gld16(const void* g, void* l) {
  __builtin_amdgcn_global_load_lds(
      (const __attribute__((address_space(1))) void*)g,
      (__attribute__((address_space(3))) void*)l, 16, 0, 0);
}

// ---------------- fp32 -> bf16 convert ----------------
__global__ __launch_bounds__(256) void cvt_kernel(const float* __restrict__ in,
                                                  u16* __restrict__ out, int n4) {
  int i = blockIdx.x * 256 + threadIdx.x;
  if (i < n4) {
    float4 v = ((const float4*)in)[i];
    ushort4 o;
    o.x = f2bf(v.x); o.y = f2bf(v.y); o.z = f2bf(v.z); o.w = f2bf(v.w);
    ((ushort4*)out)[i] = o;
  }
}

// ---------------- per-bh transpose + cvt: out[c][r] = bf16(in[r][c]) ----------------
// grid (64, (R/32)*(C/32)), 256 threads, 32x32 tiles.
__global__ __launch_bounds__(256) void transpose_cvt(const float* __restrict__ in,
                                                     u16* __restrict__ out, int R, int C) {
  __shared__ float tile[32][33];
  const int bh = blockIdx.x;
  const int nct = C >> 5;
  const int rt = blockIdx.y / nct, ct = blockIdx.y % nct;
  const float* src = in + (size_t)bh * R * C;
  u16* dst = out + (size_t)bh * R * C;
  const int r = threadIdx.x >> 3, c4 = (threadIdx.x & 7) * 4;
  float4 v = *(const float4*)(src + (size_t)(rt * 32 + r) * C + ct * 32 + c4);
  tile[r][c4 + 0] = v.x; tile[r][c4 + 1] = v.y;
  tile[r][c4 + 2] = v.z; tile[r][c4 + 3] = v.w;
  __syncthreads();
  ushort4 o;
  o.x = f2bf(tile[c4 + 0][r]); o.y = f2bf(tile[c4 + 1][r]);
  o.z = f2bf(tile[c4 + 2][r]); o.w = f2bf(tile[c4 + 3][r]);
  *(ushort4*)(dst + (size_t)(ct * 32 + r) * R + rt * 32 + c4) = o;
}

// ---------------- GEMM: C[M,N] = A[M,K] @ B[N,K]^T + bias (m97 structure) ----------------
// 128x128 tile, BK=32, 4 waves 2x2, global_load_lds width-16 staging.
template<bool OUT_BF16>
__global__ __launch_bounds__(256, 2)
void gemm_bt(const u16* __restrict__ A, const u16* __restrict__ Bm,
             const float* __restrict__ bias, void* __restrict__ Cout,
             int M, int N, int K) {
  __shared__ __align__(16) u16 As[128 * 32];
  __shared__ __align__(16) u16 Bs[128 * 32];
  const int t = threadIdx.x, lane = t & 63, w = t >> 6;
  const int row0 = blockIdx.x * 128, col0 = blockIdx.y * 128;
  const int wr = (w >> 1) * 64, wc = (w & 1) * 64;
  const int fr = lane & 15, fg = lane >> 4, fk = fg * 8;
  // staging: wave w covers rows [w*32, w*32+32) in 2 insts of 16 rows; 4 lanes/row.
  const int srow = w * 32 + (lane >> 2), scol = (lane & 3) * 8;
  const u16* gA0 = A  + (size_t)(row0 + srow) * K + scol;
  const u16* gB0 = Bm + (size_t)(col0 + srow) * K + scol;
  u16* lA0 = As + (w * 32) * 32;
  u16* lA1 = As + (w * 32 + 16) * 32;
  u16* lB0 = Bs + (w * 32) * 32;
  u16* lB1 = Bs + (w * 32 + 16) * 32;
  f32x4 acc[4][4] = {};

  for (int k0 = 0; k0 < K; k0 += 32) {
    __syncthreads();
    gld16(gA0 + k0, lA0);
    gld16(gA0 + k0 + (size_t)16 * K, lA1);
    gld16(gB0 + k0, lB0);
    gld16(gB0 + k0 + (size_t)16 * K, lB1);
    __syncthreads();
    bf16x8 af[4], bq[4];
#pragma unroll
    for (int i = 0; i < 4; i++) af[i] = *(const bf16x8*)&As[(wr + i * 16 + fr) * 32 + fk];
#pragma unroll
    for (int i = 0; i < 4; i++) bq[i] = *(const bf16x8*)&Bs[(wc + i * 16 + fr) * 32 + fk];
#pragma unroll
    for (int mi = 0; mi < 4; mi++)
#pragma unroll
      for (int ni = 0; ni < 4; ni++)
        acc[mi][ni] = __builtin_amdgcn_mfma_f32_16x16x32_bf16(af[mi], bq[ni], acc[mi][ni], 0, 0, 0);
  }

#pragma unroll
  for (int mi = 0; mi < 4; mi++)
#pragma unroll
    for (int ni = 0; ni < 4; ni++) {
      int col = col0 + wc + ni * 16 + fr;
      float bv = bias[col];
#pragma unroll
      for (int i = 0; i < 4; i++) {
        int row = row0 + wr + mi * 16 + fg * 4 + i;
        float v = acc[mi][ni][i] + bv;
        if constexpr (OUT_BF16) ((u16*)Cout)[(size_t)row * N + col] = f2bf(v);
        else                    ((float*)Cout)[(size_t)row * N + col] = v;
      }
    }
}

// ---------------- RoPE + relayout: q_proj[b*S+s][h*128+d] -> q_bf[bh][s][d] ----------------
__global__ __launch_bounds__(256) void rope_kernel(const u16* __restrict__ qp,
                                                   const float* __restrict__ cosb,
                                                   const float* __restrict__ sinb,
                                                   u16* __restrict__ qout) {
  int tid = blockIdx.x * 256 + threadIdx.x;
  int p4 = tid & 15;
  int h  = (tid >> 4) & 15;
  int s  = (tid >> 8) & 1023;
  int b  = tid >> 18;
  int d0 = p4 * 4;
  size_t qoff = ((size_t)(b * 1024 + s)) * 2048 + h * 128 + d0;
  ushort4 q1 = *(const ushort4*)(qp + qoff);
  ushort4 q2 = *(const ushort4*)(qp + qoff + 64);
  float4 c  = *(const float4*)(cosb + s * 128 + d0);
  float4 sn = *(const float4*)(sinb + s * 128 + d0);
  float q1f[4] = {bf2f(q1.x), bf2f(q1.y), bf2f(q1.z), bf2f(q1.w)};
  float q2f[4] = {bf2f(q2.x), bf2f(q2.y), bf2f(q2.z), bf2f(q2.w)};
  float cc[4]  = {c.x, c.y, c.z, c.w};
  float ssv[4] = {sn.x, sn.y, sn.z, sn.w};
  ushort4 o1, o2;
  o1.x = f2bf(q1f[0] * cc[0] - q2f[0] * ssv[0]);
  o1.y = f2bf(q1f[1] * cc[1] - q2f[1] * ssv[1]);
  o1.z = f2bf(q1f[2] * cc[2] - q2f[2] * ssv[2]);
  o1.w = f2bf(q1f[3] * cc[3] - q2f[3] * ssv[3]);
  o2.x = f2bf(q2f[0] * cc[0] + q1f[0] * ssv[0]);
  o2.y = f2bf(q2f[1] * cc[1] + q1f[1] * ssv[1]);
  o2.z = f2bf(q2f[2] * cc[2] + q1f[2] * ssv[2]);
  o2.w = f2bf(q2f[3] * cc[3] + q1f[3] * ssv[3]);
  size_t ooff = ((size_t)(b * 16 + h) * 1024 + s) * 128 + d0;
  *(ushort4*)(qout + ooff)      = o1;
  *(ushort4*)(qout + ooff + 64) = o2;
}

// ---------------- Flash attention, causal, balanced ----------------
// grid (bh=64, j=8); block = 4 waves; each block handles q-tiles {j, 15-j}
// (BQ=64 -> uniform 17 kv-tiles/block). Wave owns 16 q-rows. BKV=64.
// kT[bh][s][d], vT[bh][d][s] pre-converted bf16. P-buffer unioned with K tile.
__global__ __launch_bounds__(256, 2)
void attn_kernel(const u16* __restrict__ qbf, const u16* __restrict__ kTb,
                 const u16* __restrict__ vTb, u16* __restrict__ aout) {
  __shared__ __align__(16) u16 KP[64 * 136];   // K tile [64][136] / P [4][16][72]
  __shared__ __align__(16) u16 Vs[128 * 72];   // V^T tile [128][72]
  const int t = threadIdx.x, lane = t & 63, w = t >> 6;
  const int bh = blockIdx.x, b = bh >> 4, h = bh & 15;
  const int fr = lane & 15, fg = lane >> 4;
  const float scale = 0.088388347648318447f;   // 1/sqrt(128)
  const u16* kbase = kTb + (size_t)bh * 131072;
  const u16* vbase = vTb + (size_t)bh * 131072;
  u16* Pw = KP + w * 1152;                     // per-wave P [16][72]
  const int krow = t >> 2, kc = (t & 3) * 32;  // K staging: 4 lanes/row
  const int vrow = t >> 1, vc = (t & 1) * 32;  // V staging: 2 lanes/row
  u16* lK = KP + krow * 136 + kc;
  u16* lV = Vs + vrow * 72 + vc;
  const int rloc = w * 16 + fg * 4;            // block-local q-row base

  for (int pass = 0; pass < 2; pass++) {
    const int qt = pass ? 15 - (int)blockIdx.y : (int)blockIdx.y;
    const int q0 = qt * 64;
    bf16x8 qf[4];
#pragma unroll
    for (int kb = 0; kb < 4; kb++)
      qf[kb] = *(const bf16x8*)&qbf[((size_t)bh * 1024 + q0 + w * 16 + fr) * 128 + kb * 32 + fg * 8];
    f32x4 acc[8] = {};
    float m[4], l[4];
#pragma unroll
    for (int i = 0; i < 4; i++) { m[i] = -3e38f; l[i] = 0.f; }

    for (int kt = 0; kt <= qt; kt++) {
      __syncthreads();                         // prev PV done (P & V reuse)
      {
        const u16* gK = kbase + (size_t)(kt * 64 + krow) * 128 + kc;
        const u16* gV = vbase + (size_t)vrow * 1024 + kt * 64 + vc;
#pragma unroll
        for (int p = 0; p < 4; p++) {
          *(int4*)(lK + p * 8) = *(const int4*)(gK + p * 8);
          *(int4*)(lV + p * 8) = *(const int4*)(gV + p * 8);
        }
      }
      __syncthreads();
      // QK^T: wave's 16 q-rows x 64 kv-cols
      f32x4 sa[4] = {};
#pragma unroll
      for (int kb = 0; kb < 4; kb++) {
        bf16x8 kf[4];
#pragma unroll
        for (int ni = 0; ni < 4; ni++)
          kf[ni] = *(const bf16x8*)&KP[(ni * 16 + fr) * 136 + kb * 32 + fg * 8];
#pragma unroll
        for (int ni = 0; ni < 4; ni++)
          sa[ni] = __builtin_amdgcn_mfma_f32_16x16x32_bf16(qf[kb], kf[ni], sa[ni], 0, 0, 0);
      }
      __syncthreads();                         // all waves done reading K (P overwrites it)
      // online softmax; rows rloc+i, cols ni*16+fr
      const bool diag = (kt == qt);
      float tmax[4] = {-3e38f, -3e38f, -3e38f, -3e38f};
#pragma unroll
      for (int ni = 0; ni < 4; ni++) {
        int cloc = ni * 16 + fr;
#pragma unroll
        for (int i = 0; i < 4; i++) {
          float s = sa[ni][i] * scale;
          if (diag && cloc > rloc + i) s = -1e9f;
          sa[ni][i] = s;
          tmax[i] = fmaxf(tmax[i], s);
        }
      }
#pragma unroll
      for (int msk = 1; msk < 16; msk <<= 1)
#pragma unroll
        for (int i = 0; i < 4; i++) tmax[i] = fmaxf(tmax[i], __shfl_xor(tmax[i], msk));
      float corr[4];
#pragma unroll
      for (int i = 0; i < 4; i++) {
        float mn = fmaxf(m[i], tmax[i]);
        corr[i] = __expf(m[i] - mn);
        m[i] = mn;
      }
      float rs[4] = {0.f, 0.f, 0.f, 0.f};
#pragma unroll
      for (int ni = 0; ni < 4; ni++)
#pragma unroll
        for (int i = 0; i < 4; i++) {
          float p = __expf(sa[ni][i] - m[i]);
          sa[ni][i] = p;
          rs[i] += p;
        }
#pragma unroll
      for (int msk = 1; msk < 16; msk <<= 1)
#pragma unroll
        for (int i = 0; i < 4; i++) rs[i] += __shfl_xor(rs[i], msk);
#pragma unroll
      for (int i = 0; i < 4; i++) l[i] = l[i] * corr[i] + rs[i];
#pragma unroll
      for (int ni = 0; ni < 8; ni++)
#pragma unroll
        for (int i = 0; i < 4; i++) acc[ni][i] *= corr[i];
#pragma unroll
      for (int ni = 0; ni < 4; ni++)
#pragma unroll
        for (int i = 0; i < 4; i++)
          Pw[(fg * 4 + i) * 72 + ni * 16 + fr] = f2bf(sa[ni][i]);
      // PV: own-wave P (wave-local ds ordering), shared V
#pragma unroll
      for (int kb2 = 0; kb2 < 2; kb2++) {
        bf16x8 pf = *(const bf16x8*)&Pw[fr * 72 + kb2 * 32 + fg * 8];
#pragma unroll
        for (int ni = 0; ni < 8; ni++) {
          bf16x8 vf = *(const bf16x8*)&Vs[(ni * 16 + fr) * 72 + kb2 * 32 + fg * 8];
          acc[ni] = __builtin_amdgcn_mfma_f32_16x16x32_bf16(pf, vf, acc[ni], 0, 0, 0);
        }
      }
    }
    // epilogue: attn_bf[((b*S+s)*NH+h)*HD + d]
#pragma unroll
    for (int i = 0; i < 4; i++) {
      int s = q0 + w * 16 + fg * 4 + i;
      float inv = 1.f / l[i];
#pragma unroll
      for (int ni = 0; ni < 8; ni++)
        aout[(((size_t)b * 1024 + s) * 16 + h) * 128 + ni * 16 + fr] = f2bf(acc[ni][i] * inv);
    }
  }
}

// ---------------- launcher ----------------
extern "C" void kernel_launch(void* const* d_in, const int* in_sizes, int n_in,
                              void* d_out, int out_size, void* d_ws, size_t ws_size,
                              hipStream_t stream) {
  const float* hs  = (const float*)d_in[0];
  const float* key = (const float*)d_in[1];
  const float* val = (const float*)d_in[2];
  // d_in[3]: attention_mask — causal, reproduced analytically
  const float* rc  = (const float*)d_in[4];
  const float* rs  = (const float*)d_in[5];
  const float* wq  = (const float*)d_in[6];
  const float* bq  = (const float*)d_in[7];
  const float* wo  = (const float*)d_in[8];
  const float* bo  = (const float*)d_in[9];
  float* out = (float*)d_out;

  char* ws = (char*)d_ws;
  u16* hs_bf   = (u16*)(ws);                 // 16.78 MB ; reused as attn_bf
  u16* wq_bf   = (u16*)(ws + 16777216);      //  8.39 MB
  u16* wo_bf   = (u16*)(ws + 25165824);      //  8.39 MB
  u16* q_proj  = (u16*)(ws + 33554432);      // 16.78 MB ; reused as kT
  u16* q_bf    = (u16*)(ws + 50331648);      // 16.78 MB
  u16* vT      = (u16*)(ws + 67108864);      // 16.78 MB  (total 80 MiB)
  u16* attn_bf = hs_bf;                      // hs_bf dead after gemm1
  u16* kT      = q_proj;                     // q_proj dead after rope

  cvt_kernel<<<8192, 256, 0, stream>>>(hs, hs_bf, 8388608 / 4);
  cvt_kernel<<<4096, 256, 0, stream>>>(wq, wq_bf, 4194304 / 4);
  cvt_kernel<<<4096, 256, 0, stream>>>(wo, wo_bf, 4194304 / 4);

  gemm_bt<true><<<dim3(32, 16), 256, 0, stream>>>(hs_bf, wq_bf, bq, q_proj, 4096, 2048, 2048);
  rope_kernel<<<4096, 256, 0, stream>>>(q_proj, rc, rs, q_bf);

  transpose_cvt<<<dim3(64, 128), 256, 0, stream>>>(key, kT, 128, 1024);   // -> kT[bh][s][d]
  transpose_cvt<<<dim3(64, 128), 256, 0, stream>>>(val, vT, 1024, 128);   // -> vT[bh][d][s]

  attn_kernel<<<dim3(64, 8), 256, 0, stream>>>(q_bf, kT, vT, attn_bf);
  gemm_bt<false><<<dim3(32, 16), 256, 0, stream>>>(attn_bf, wo_bf, bo, out, 4096, 2048, 2048);
}